// Round 6
// baseline (164.712 us; speedup 1.0000x reference)
//
#include <hip/hip_runtime.h>
#include <stdint.h>

#define B_ROWS 4096
#define D_DIM  512
#define N_TOT  8192
#define TEMP_INV 2.0f   // 1/0.5
#define NB     64       // N_TOT / 128 tiles per dim
#define NTRI   2080     // NB*(NB+1)/2

typedef __bf16 bf16x8 __attribute__((ext_vector_type(8)));
typedef float  f32x4  __attribute__((ext_vector_type(4)));
typedef unsigned short ushort8 __attribute__((ext_vector_type(8)));

__device__ __forceinline__ unsigned short f2bf(float f) {
    union { float f; unsigned int u; } c; c.f = f;
    unsigned int u = c.u;
    return (unsigned short)((u + 0x7fffu + ((u >> 16) & 1u)) >> 16);
}

// async global->LDS, 16B per lane. LDS dest is wave-uniform base + lane*16.
__device__ __forceinline__ void gl_lds16(const void* g, void* l) {
    __builtin_amdgcn_global_load_lds(
        (__attribute__((address_space(1))) void*)(uintptr_t)g,
        (__attribute__((address_space(3))) void*)(uintptr_t)l,
        16, 0, 0);
}

// ------- kernel 1: fused L2-normalize (write bf16 z) + positive-pair dot -------
// also zero-inits rowsum[] and the completion counter for kernel 2's tail.
__global__ __launch_bounds__(256) void normpos_kernel(
    const float* __restrict__ xi, const float* __restrict__ xj,
    unsigned short* __restrict__ z, float* __restrict__ pos,
    float* __restrict__ rowsum, unsigned int* __restrict__ counter) {
    if (blockIdx.x < 32) rowsum[blockIdx.x * 256 + threadIdx.x] = 0.f;
    if (blockIdx.x == 32 && threadIdx.x == 0) *counter = 0u;

    const int wid  = threadIdx.x >> 6;
    const int lane = threadIdx.x & 63;
    const int k    = blockIdx.x * 4 + wid;
    const float4* a4 = (const float4*)(xi + (size_t)k * D_DIM);
    const float4* b4 = (const float4*)(xj + (size_t)k * D_DIM);
    float4 va0 = a4[2 * lane], va1 = a4[2 * lane + 1];
    float4 vb0 = b4[2 * lane], vb1 = b4[2 * lane + 1];
    float ssa = va0.x*va0.x + va0.y*va0.y + va0.z*va0.z + va0.w*va0.w
              + va1.x*va1.x + va1.y*va1.y + va1.z*va1.z + va1.w*va1.w;
    float ssb = vb0.x*vb0.x + vb0.y*vb0.y + vb0.z*vb0.z + vb0.w*vb0.w
              + vb1.x*vb1.x + vb1.y*vb1.y + vb1.z*vb1.z + vb1.w*vb1.w;
    float dot = va0.x*vb0.x + va0.y*vb0.y + va0.z*vb0.z + va0.w*vb0.w
              + va1.x*vb1.x + va1.y*vb1.y + va1.z*vb1.z + va1.w*vb1.w;
    #pragma unroll
    for (int m = 32; m >= 1; m >>= 1) {
        ssa += __shfl_xor(ssa, m);
        ssb += __shfl_xor(ssb, m);
        dot += __shfl_xor(dot, m);
    }
    const float rna = 1.0f / fmaxf(sqrtf(ssa), 1e-12f);
    const float rnb = 1.0f / fmaxf(sqrtf(ssb), 1e-12f);
    float av[8] = {va0.x, va0.y, va0.z, va0.w, va1.x, va1.y, va1.z, va1.w};
    float bv[8] = {vb0.x, vb0.y, vb0.z, vb0.w, vb1.x, vb1.y, vb1.z, vb1.w};
    union { ushort8 v; unsigned short s[8]; } oa, ob;
    #pragma unroll
    for (int i = 0; i < 8; ++i) {
        oa.s[i] = f2bf(av[i] * rna);
        ob.s[i] = f2bf(bv[i] * rnb);
    }
    *(ushort8*)(z + (size_t)k * D_DIM + lane * 8) = oa.v;
    *(ushort8*)(z + (size_t)(k + B_ROWS) * D_DIM + lane * 8) = ob.v;
    if (lane == 0) pos[k] = dot * rna * rnb;
}

// -------- kernel 2: symmetric fused Gram-row-sum over upper-triangular tiles --------
// EXACT R2 structure (proven 62 us, 0 bank conflicts): 128x128 tile, 4 waves (2x2),
// each wave 64x64 via 4x4 mfma_f32_16x16x32_bf16, BK=32, 16 kt-iterations,
// 2 barriers/kt, LDS k-chunk XOR swizzle. Off-diag tiles also contribute column
// sums (symmetry). Last-arriving block computes the final scalar loss (fused tail).
__global__ __launch_bounds__(256) void simrow_kernel(
    const unsigned short* __restrict__ z, float* __restrict__ rowsum,
    const float* __restrict__ pos, unsigned int* __restrict__ counter,
    float* __restrict__ out) {
    __shared__ unsigned short As[128 * 32];  // 8 KB
    __shared__ unsigned short Bs[128 * 32];  // 8 KB
    __shared__ float rsum[128];
    __shared__ float csum[128];
    __shared__ float red[8];
    __shared__ unsigned int lastFlag;
    const int tid  = threadIdx.x;
    const int lane = tid & 63;
    const int wid  = tid >> 6;

    // map linear block id -> upper-triangular (bi, bj), bi <= bj
    const int t0 = blockIdx.x;
    int bi = (int)(NB + 0.5f - sqrtf((NB + 0.5f) * (NB + 0.5f) - 2.0f * t0));
    if (bi < 0) bi = 0;
    if (bi > NB - 1) bi = NB - 1;
    while (bi > 0 && (bi * NB - bi * (bi - 1) / 2) > t0) --bi;
    while ((bi + 1) * NB - (bi + 1) * bi / 2 <= t0) ++bi;
    const int bj = bi + (t0 - (bi * NB - bi * (bi - 1) / 2));
    const int row0 = bi * 128;
    const int col0 = bj * 128;
    const bool diag = (bi == bj);

    if (tid < 128) { rsum[tid] = 0.f; csum[tid] = 0.f; }

    const int wr = wid >> 1, wc = wid & 1;
    f32x4 acc[4][4] = {};

    // staging: lane -> (row = wid*16 + (lane>>2), slot = lane&3)
    // slot c stores global k-chunk c ^ ((row>>1)&3); here (row>>1)&3 == (lane>>3)&3
    const int srow = wid * 16 + (lane >> 2);
    const int skc  = ((lane & 3) ^ ((lane >> 3) & 3)) * 8;

    for (int kt = 0; kt < D_DIM / 32; ++kt) {
        const int k0 = kt * 32;
        #pragma unroll
        for (int t = 0; t < 2; ++t) {
            const int r = t * 64 + srow;
            gl_lds16(z + (size_t)(row0 + r) * D_DIM + k0 + skc,
                     &As[t * 2048 + wid * 512]);
            if (!diag)
                gl_lds16(z + (size_t)(col0 + r) * D_DIM + k0 + skc,
                         &Bs[t * 2048 + wid * 512]);
        }
        __syncthreads();
        const unsigned short* Bsrc = diag ? As : Bs;
        const int kqi = lane >> 4;         // desired global k-chunk
        const int ml  = lane & 15;
        const int sw  = (ml >> 1) & 3;     // swizzle term for this row parity
        const int slot = (kqi ^ sw) * 8;
        bf16x8 af[4], bfr[4];
        #pragma unroll
        for (int mi = 0; mi < 4; ++mi)
            af[mi] = *(const bf16x8*)&As[(wr * 64 + mi * 16 + ml) * 32 + slot];
        #pragma unroll
        for (int ni = 0; ni < 4; ++ni)
            bfr[ni] = *(const bf16x8*)&Bsrc[(wc * 64 + ni * 16 + ml) * 32 + slot];
        #pragma unroll
        for (int mi = 0; mi < 4; ++mi)
            #pragma unroll
            for (int ni = 0; ni < 4; ++ni)
                acc[mi][ni] = __builtin_amdgcn_mfma_f32_16x16x32_bf16(
                    af[mi], bfr[ni], acc[mi][ni], 0, 0, 0);
        __syncthreads();
    }

    // epilogue: e = exp(2*sim), mask diagonal; row sums always, col sums if off-diag
    const int quad = lane >> 4;
    const int cl   = lane & 15;
    float colacc[4] = {0.f, 0.f, 0.f, 0.f};
    #pragma unroll
    for (int mi = 0; mi < 4; ++mi) {
        #pragma unroll
        for (int r = 0; r < 4; ++r) {
            const int lrow = wr * 64 + mi * 16 + quad * 4 + r;
            const int irow = row0 + lrow;
            float s = 0.f;
            #pragma unroll
            for (int ni = 0; ni < 4; ++ni) {
                const int jcol = col0 + wc * 64 + ni * 16 + cl;
                float e = __expf(TEMP_INV * acc[mi][ni][r]);
                e = (irow == jcol) ? 0.f : e;
                s += e;
                colacc[ni] += e;
            }
            s += __shfl_xor(s, 1);
            s += __shfl_xor(s, 2);
            s += __shfl_xor(s, 4);
            s += __shfl_xor(s, 8);
            if (cl == 0) atomicAdd(&rsum[lrow], s);
        }
    }
    if (!diag) {
        #pragma unroll
        for (int ni = 0; ni < 4; ++ni) {
            float c = colacc[ni];
            c += __shfl_xor(c, 16);
            c += __shfl_xor(c, 32);
            if (quad == 0) atomicAdd(&csum[wc * 64 + ni * 16 + cl], c);
        }
    }
    __syncthreads();
    if (tid < 128) {
        atomicAdd(&rowsum[row0 + tid], rsum[tid]);
        if (!diag) atomicAdd(&rowsum[col0 + tid], csum[tid]);
    }

    // ---- tail: last-arriving block computes the scalar loss ----
    if (tid == 0) {
        __threadfence();                         // release our rowsum adds
        unsigned int old = atomicAdd(counter, 1u);
        lastFlag = (old == NTRI - 1) ? 1u : 0u;
    }
    __syncthreads();
    if (lastFlag) {
        __threadfence();                         // acquire others' adds
        float s = 0.f, pacc = 0.f;
        for (int i = tid; i < N_TOT; i += 256) {
            float rv = __hip_atomic_load(&rowsum[i], __ATOMIC_RELAXED,
                                         __HIP_MEMORY_SCOPE_AGENT);
            s += logf(rv);
        }
        for (int i = tid; i < B_ROWS; i += 256) pacc += pos[i];
        #pragma unroll
        for (int m = 32; m >= 1; m >>= 1) {
            s += __shfl_xor(s, m);
            pacc += __shfl_xor(pacc, m);
        }
        if (lane == 0) { red[wid] = s; red[4 + wid] = pacc; }
        __syncthreads();
        if (tid == 0) {
            float tot = red[0] + red[1] + red[2] + red[3];
            float pt  = red[4] + red[5] + red[6] + red[7];
            // loss = mean(log denom) - (2*posSum)/(temp*N)
            out[0] = tot / (float)N_TOT - pt * (2.0f * TEMP_INV / (float)N_TOT);
        }
    }
}

extern "C" void kernel_launch(void* const* d_in, const int* in_sizes, int n_in,
                              void* d_out, int out_size, void* d_ws, size_t ws_size,
                              hipStream_t stream) {
    const float* xi = (const float*)d_in[0];
    const float* xj = (const float*)d_in[1];
    float* out = (float*)d_out;
    char* ws = (char*)d_ws;

    unsigned short* z = (unsigned short*)ws;                       // 8 MB bf16
    float* rowsum = (float*)(ws + (size_t)N_TOT * D_DIM * 2);      // 32 KB
    float* pos = rowsum + N_TOT;                                   // 16 KB
    unsigned int* counter = (unsigned int*)(pos + B_ROWS);         // 4 B

    normpos_kernel<<<B_ROWS / 4, 256, 0, stream>>>(xi, xj, z, pos, rowsum, counter);
    simrow_kernel<<<NTRI, 256, 0, stream>>>(z, rowsum, pos, counter, out);
}

// Round 7
// 134.716 us; speedup vs baseline: 1.2227x; 1.2227x over previous
//
#include <hip/hip_runtime.h>
#include <stdint.h>

#define B_ROWS 4096
#define D_DIM  512          // elements; z is 1 byte/elem (fp8 e4m3)
#define N_TOT  8192
#define TEMP_INV 2.0f       // 1/0.5
#define NB     64           // N_TOT / 128 tiles per dim
#define NTRI   2080         // NB*(NB+1)/2

typedef float f32x4 __attribute__((ext_vector_type(4)));
typedef long  lng2  __attribute__((ext_vector_type(2)));

// async global->LDS, 16B per lane. LDS dest is wave-uniform base + lane*16.
__device__ __forceinline__ void gl_lds16(const void* g, void* l) {
    __builtin_amdgcn_global_load_lds(
        (__attribute__((address_space(1))) void*)(uintptr_t)g,
        (__attribute__((address_space(3))) void*)(uintptr_t)l,
        16, 0, 0);
}

// ------- kernel 1: fused L2-normalize (write fp8-e4m3 z) + positive-pair dot -------
// also zero-inits rowsum[] and the completion counter for kernel 2's tail.
__global__ __launch_bounds__(256) void normpos_kernel(
    const float* __restrict__ xi, const float* __restrict__ xj,
    unsigned char* __restrict__ z, float* __restrict__ pos,
    float* __restrict__ rowsum, unsigned int* __restrict__ counter) {
    if (blockIdx.x < 32) rowsum[blockIdx.x * 256 + threadIdx.x] = 0.f;
    if (blockIdx.x == 32 && threadIdx.x == 0) *counter = 0u;

    const int wid  = threadIdx.x >> 6;
    const int lane = threadIdx.x & 63;
    const int k    = blockIdx.x * 4 + wid;
    const float4* a4 = (const float4*)(xi + (size_t)k * D_DIM);
    const float4* b4 = (const float4*)(xj + (size_t)k * D_DIM);
    float4 va0 = a4[2 * lane], va1 = a4[2 * lane + 1];
    float4 vb0 = b4[2 * lane], vb1 = b4[2 * lane + 1];
    float ssa = va0.x*va0.x + va0.y*va0.y + va0.z*va0.z + va0.w*va0.w
              + va1.x*va1.x + va1.y*va1.y + va1.z*va1.z + va1.w*va1.w;
    float ssb = vb0.x*vb0.x + vb0.y*vb0.y + vb0.z*vb0.z + vb0.w*vb0.w
              + vb1.x*vb1.x + vb1.y*vb1.y + vb1.z*vb1.z + vb1.w*vb1.w;
    float dot = va0.x*vb0.x + va0.y*vb0.y + va0.z*vb0.z + va0.w*vb0.w
              + va1.x*vb1.x + va1.y*vb1.y + va1.z*vb1.z + va1.w*vb1.w;
    #pragma unroll
    for (int m = 32; m >= 1; m >>= 1) {
        ssa += __shfl_xor(ssa, m);
        ssb += __shfl_xor(ssb, m);
        dot += __shfl_xor(dot, m);
    }
    const float rna = 1.0f / fmaxf(sqrtf(ssa), 1e-12f);
    const float rnb = 1.0f / fmaxf(sqrtf(ssb), 1e-12f);
    // pack 8 normalized values -> 8 fp8 e4m3 bytes (RNE via v_cvt_pk_fp8_f32)
    unsigned int aw0 = 0, aw1 = 0, bw0 = 0, bw1 = 0;
    aw0 = __builtin_amdgcn_cvt_pk_fp8_f32(va0.x * rna, va0.y * rna, aw0, false);
    aw0 = __builtin_amdgcn_cvt_pk_fp8_f32(va0.z * rna, va0.w * rna, aw0, true);
    aw1 = __builtin_amdgcn_cvt_pk_fp8_f32(va1.x * rna, va1.y * rna, aw1, false);
    aw1 = __builtin_amdgcn_cvt_pk_fp8_f32(va1.z * rna, va1.w * rna, aw1, true);
    bw0 = __builtin_amdgcn_cvt_pk_fp8_f32(vb0.x * rnb, vb0.y * rnb, bw0, false);
    bw0 = __builtin_amdgcn_cvt_pk_fp8_f32(vb0.z * rnb, vb0.w * rnb, bw0, true);
    bw1 = __builtin_amdgcn_cvt_pk_fp8_f32(vb1.x * rnb, vb1.y * rnb, bw1, false);
    bw1 = __builtin_amdgcn_cvt_pk_fp8_f32(vb1.z * rnb, vb1.w * rnb, bw1, true);
    *(uint2*)(z + (size_t)k * D_DIM + lane * 8) = make_uint2(aw0, aw1);
    *(uint2*)(z + (size_t)(k + B_ROWS) * D_DIM + lane * 8) = make_uint2(bw0, bw1);
    if (lane == 0) pos[k] = dot * rna * rnb;
}

// -------- kernel 2: symmetric Gram row-sums, fp8, 128x128 tile, BK=64 --------
// R5's core (fence-free tail): 256 thr = 4 waves (2x2), each wave 64x64 via 4x4 of
// mfma_f32_16x16x32_fp8_fp8 (x2 k-steps per kt), 8 kt-iterations, 2 barriers/kt.
// LDS rows are 64 B (K=64 fp8); 16B-chunk slot = chunk ^ ((row>>1)&3) XOR swizzle
// (0 conflicts measured in R5). Fused finalize tail WITHOUT __threadfence():
// release = __syncthreads() (compiler drains vmcnt before s_barrier, so each
// wave's device-coherent rowsum atomics are complete) + relaxed agent counter add;
// acquire = agent-scope (cache-bypassing) atomic loads of rowsum in the winner.
__global__ __launch_bounds__(256) void simrow_kernel(
    const unsigned char* __restrict__ z, float* __restrict__ rowsum,
    const float* __restrict__ pos, unsigned int* __restrict__ counter,
    float* __restrict__ out) {
    __shared__ __align__(16) char As[128 * 64];  // 8 KB
    __shared__ __align__(16) char Bs[128 * 64];  // 8 KB
    __shared__ float rsum[128];
    __shared__ float csum[128];
    __shared__ float red[8];
    __shared__ unsigned int lastFlag;

    const int tid  = threadIdx.x;
    const int lane = tid & 63;
    const int wid  = tid >> 6;

    // map linear block id -> upper-triangular (bi, bj), bi <= bj
    const int t0 = blockIdx.x;
    int bi = (int)(NB + 0.5f - sqrtf((NB + 0.5f) * (NB + 0.5f) - 2.0f * t0));
    if (bi < 0) bi = 0;
    if (bi > NB - 1) bi = NB - 1;
    while (bi > 0 && (bi * NB - bi * (bi - 1) / 2) > t0) --bi;
    while ((bi + 1) * NB - (bi + 1) * bi / 2 <= t0) ++bi;
    const int bj = bi + (t0 - (bi * NB - bi * (bi - 1) / 2));
    const int row0 = bi * 128;
    const int col0 = bj * 128;
    const bool diag = (bi == bj);

    if (tid < 128) { rsum[tid] = 0.f; csum[tid] = 0.f; }

    const int wr = wid >> 1, wc = wid & 1;
    f32x4 acc[4][4] = {};

    // staging: per issue-half i, lane -> row = i*64 + wid*16 + (lane>>2),
    // LDS slot = lane&3 holds global chunk (lane&3)^((row>>1)&3);
    // ((row>>1)&3) == ((lane>>3)&3). LDS addr = base + lane*16 (linear, required).
    const int srow = wid * 16 + (lane >> 2);
    const int gch  = ((lane & 3) ^ ((lane >> 3) & 3)) * 16;  // global byte chunk

    const int ml = lane & 15;
    const int kh = lane >> 4;

    for (int kt = 0; kt < 8; ++kt) {
        const int k0 = kt * 64;
        #pragma unroll
        for (int i = 0; i < 2; ++i) {
            const int r = i * 64 + srow;
            gl_lds16(z + (size_t)(row0 + r) * D_DIM + k0 + gch,
                     &As[(i * 64 + wid * 16) * 64]);
            if (!diag)
                gl_lds16(z + (size_t)(col0 + r) * D_DIM + k0 + gch,
                         &Bs[(i * 64 + wid * 16) * 64]);
        }
        __syncthreads();
        const char* Asrc = As;
        const char* Bsrc = diag ? As : Bs;
        // fragment: row r, want global chunk kh -> LDS slot kh ^ ((r>>1)&3)
        lng2 af[4], bfr[4];
        #pragma unroll
        for (int mi = 0; mi < 4; ++mi) {
            const int r = wr * 64 + mi * 16 + ml;
            af[mi] = *(const lng2*)&Asrc[r * 64 + ((kh ^ ((r >> 1) & 3)) * 16)];
        }
        #pragma unroll
        for (int ni = 0; ni < 4; ++ni) {
            const int r = wc * 64 + ni * 16 + ml;
            bfr[ni] = *(const lng2*)&Bsrc[r * 64 + ((kh ^ ((r >> 1) & 3)) * 16)];
        }
        #pragma unroll
        for (int s = 0; s < 2; ++s) {
            #pragma unroll
            for (int mi = 0; mi < 4; ++mi)
                #pragma unroll
                for (int ni = 0; ni < 4; ++ni)
                    acc[mi][ni] = __builtin_amdgcn_mfma_f32_16x16x32_fp8_fp8(
                        s ? af[mi].y : af[mi].x,
                        s ? bfr[ni].y : bfr[ni].x,
                        acc[mi][ni], 0, 0, 0);
        }
        __syncthreads();
    }

    // epilogue: C/D 16x16 layout col=lane&15, row=(lane>>4)*4+reg.
    const int quad = lane >> 4;
    const int cl   = lane & 15;
    float colacc[4] = {0.f, 0.f, 0.f, 0.f};
    #pragma unroll
    for (int mi = 0; mi < 4; ++mi) {
        #pragma unroll
        for (int r2 = 0; r2 < 4; ++r2) {
            const int lrow = wr * 64 + mi * 16 + quad * 4 + r2;
            const int irow = row0 + lrow;
            float s = 0.f;
            #pragma unroll
            for (int ni = 0; ni < 4; ++ni) {
                const int jcol = col0 + wc * 64 + ni * 16 + cl;
                float e = __expf(TEMP_INV * acc[mi][ni][r2]);
                e = (irow == jcol) ? 0.f : e;
                s += e;
                colacc[ni] += e;
            }
            s += __shfl_xor(s, 1);
            s += __shfl_xor(s, 2);
            s += __shfl_xor(s, 4);
            s += __shfl_xor(s, 8);
            if (cl == 0) atomicAdd(&rsum[lrow], s);
        }
    }
    if (!diag) {
        #pragma unroll
        for (int ni = 0; ni < 4; ++ni) {
            float c = colacc[ni];
            c += __shfl_xor(c, 16);
            c += __shfl_xor(c, 32);
            if (quad == 0) atomicAdd(&csum[wc * 64 + ni * 16 + cl], c);
        }
    }
    __syncthreads();
    if (tid < 128) {
        atomicAdd(&rowsum[row0 + tid], rsum[tid]);
        if (!diag) atomicAdd(&rowsum[col0 + tid], csum[tid]);
    }
    // release: __syncthreads() forces each wave to drain vmcnt (incl. the
    // device-coherent rowsum atomics) before any thread passes the barrier.
    __syncthreads();

    // ---- tail: last-arriving block computes the scalar loss (no L2 flush) ----
    if (tid == 0) {
        unsigned int old = __hip_atomic_fetch_add(counter, 1u, __ATOMIC_RELAXED,
                                                  __HIP_MEMORY_SCOPE_AGENT);
        lastFlag = (old == NTRI - 1) ? 1u : 0u;
    }
    __syncthreads();
    if (lastFlag) {
        float s = 0.f, pacc = 0.f;
        for (int i = tid; i < N_TOT; i += 256) {
            // agent-scope load: bypasses stale L1/L2, reads the coherent point
            float rv = __hip_atomic_load(&rowsum[i], __ATOMIC_RELAXED,
                                         __HIP_MEMORY_SCOPE_AGENT);
            s += logf(rv);
        }
        for (int i = tid; i < B_ROWS; i += 256) pacc += pos[i];
        #pragma unroll
        for (int m = 32; m >= 1; m >>= 1) {
            s += __shfl_xor(s, m);
            pacc += __shfl_xor(pacc, m);
        }
        if (lane == 0) { red[wid] = s; red[4 + wid] = pacc; }
        __syncthreads();
        if (tid == 0) {
            float tot = red[0] + red[1] + red[2] + red[3];
            float pt  = red[4] + red[5] + red[6] + red[7];
            // loss = mean(log denom) - (2*posSum)/(temp*N)
            out[0] = tot / (float)N_TOT - pt * (2.0f * TEMP_INV / (float)N_TOT);
        }
    }
}

extern "C" void kernel_launch(void* const* d_in, const int* in_sizes, int n_in,
                              void* d_out, int out_size, void* d_ws, size_t ws_size,
                              hipStream_t stream) {
    const float* xi = (const float*)d_in[0];
    const float* xj = (const float*)d_in[1];
    float* out = (float*)d_out;
    char* ws = (char*)d_ws;

    unsigned char* z = (unsigned char*)ws;                    // 4 MB fp8
    float* rowsum = (float*)(ws + (size_t)N_TOT * D_DIM);     // 32 KB
    float* pos = rowsum + N_TOT;                              // 16 KB
    unsigned int* counter = (unsigned int*)(pos + B_ROWS);    // 4 B

    normpos_kernel<<<B_ROWS / 4, 256, 0, stream>>>(xi, xj, z, pos, rowsum, counter);
    simrow_kernel<<<NTRI, 256, 0, stream>>>(z, rowsum, pos, counter, out);
}